// Round 2
// baseline (3368.184 us; speedup 1.0000x reference)
//
#include <hip/hip_runtime.h>

#define N_TOK 131072
#define KC    1024
#define DIM   256
#define TM    64
#define TN    64
#define LDST  260          // LDS row stride (floats): 16B-aligned rows, breaks power-of-2 bank strides

// ws layout: [0..8) double loss_sum ; [64 ..) int best_idx[N_TOK] ; then float cnorm[KC]

__global__ void vq_init(double* loss_sum) {
    if (threadIdx.x == 0) *loss_sum = 0.0;
}

__global__ void vq_cnorm(const float* __restrict__ cb, float* __restrict__ cnorm) {
    int code = blockIdx.x * 256 + threadIdx.x;
    const float* c = cb + (size_t)code * DIM;
    double sd = 0.0;
    for (int d = 0; d < DIM; ++d) { double cv = (double)c[d]; sd = fma(cv, cv, sd); }
    cnorm[code] = (float)sd;   // matches np f32 pairwise sum to ~1e-12 (value ~1e-4)
}

// Distance GEMM replicating numpy-f32 semantics:
//   e[n,k]  : strict sequential-k f32 FMA (bit-matches BLAS sgemm accumulation)
//   d[n,k]  = fl( fl(zz_n + cc_k) - fl(2*e) )   (reference op order)
//   argmin  : lowest index wins on exact f32 ties (np.argmin semantics)
// Block: 256 thr = 16(tx: codes) x 16(ty: rows); thread tile 4 rows x 4 codes.
__global__ __launch_bounds__(256)
void vq_scores(const float* __restrict__ z, const float* __restrict__ cb,
               const float* __restrict__ cnorm, int* __restrict__ best_idx)
{
    __shared__ float zA[TM][LDST];
    __shared__ float cA[TN][LDST];
    __shared__ float zzf[TM];
    __shared__ float ccf[KC];
    const int tid = threadIdx.x;
    const int tx = tid & 15;
    const int ty = tid >> 4;
    const int row0 = blockIdx.x * TM;

    // stage z tile (64 rows x 256 f32) + full cnorm (4 KB)
    {
        const float4* zg = (const float4*)(z + (size_t)row0 * DIM);
        #pragma unroll
        for (int t = 0; t < 16; ++t) {
            int f = tid + t * 256;
            int r = f >> 6;
            int c = f & 63;
            float4 v = zg[(size_t)r * 64 + c];
            *(float4*)&zA[r][c * 4] = v;
        }
        *(float4*)&ccf[tid * 4] = ((const float4*)cnorm)[tid];
    }
    __syncthreads();
    // zz per local row, f64 -> f32 (uniform-shift invariance makes order irrelevant)
    if (tid < TM) {
        double s = 0.0;
        for (int d = 0; d < DIM; ++d) { double v = (double)zA[tid][d]; s = fma(v, v, s); }
        zzf[tid] = (float)s;
    }

    float rm1[4]; int ridx[4];
    #pragma unroll
    for (int i = 0; i < 4; ++i) { rm1[i] = 3.0e38f; ridx[i] = 0; }

    for (int nc = 0; nc < KC / TN; ++nc) {
        __syncthreads();              // protects cA reuse; publishes zzf on first iter
        {
            const float4* cg = (const float4*)(cb + (size_t)nc * TN * DIM);
            #pragma unroll
            for (int t = 0; t < 16; ++t) {
                int f = tid + t * 256;
                int r = f >> 6;
                int c = f & 63;
                float4 v = cg[(size_t)r * 64 + c];
                *(float4*)&cA[r][c * 4] = v;
            }
        }
        __syncthreads();

        float acc[4][4];
        #pragma unroll
        for (int i = 0; i < 4; ++i)
            #pragma unroll
            for (int j = 0; j < 4; ++j) acc[i][j] = 0.0f;

        // strict sequential k: d4 ascending, x,y,z,w ascending -> k = 0..255 in order
        #pragma unroll 8
        for (int d4 = 0; d4 < 64; ++d4) {
            float4 zr[4], cr[4];
            #pragma unroll
            for (int i = 0; i < 4; ++i) zr[i] = *(const float4*)&zA[ty * 4 + i][d4 * 4];
            #pragma unroll
            for (int j = 0; j < 4; ++j) cr[j] = *(const float4*)&cA[j * 16 + tx][d4 * 4];
            #pragma unroll
            for (int i = 0; i < 4; ++i)
                #pragma unroll
                for (int j = 0; j < 4; ++j) {
                    acc[i][j] = fmaf(zr[i].x, cr[j].x, acc[i][j]);
                    acc[i][j] = fmaf(zr[i].y, cr[j].y, acc[i][j]);
                    acc[i][j] = fmaf(zr[i].z, cr[j].z, acc[i][j]);
                    acc[i][j] = fmaf(zr[i].w, cr[j].w, acc[i][j]);
                }
        }

        #pragma unroll
        for (int i = 0; i < 4; ++i) {
            float zz = zzf[ty * 4 + i];
            float c1 = 3.0e38f; int ci = 0;
            #pragma unroll
            for (int j = 0; j < 4; ++j) {
                int code = nc * TN + j * 16 + tx;      // ascending in j
                float A  = zz + ccf[code];             // fl(zz + cc)
                float dq = A - 2.0f * acc[i][j];       // fl(A - fl(2e)); 2e exact
                if (dq < c1) { c1 = dq; ci = code; }   // strict < keeps lowest code
            }
            // merge across the 16 tx lanes, lowest index on ties
            #pragma unroll
            for (int off = 1; off < 16; off <<= 1) {
                float o1 = __shfl_xor(c1, off, 16);
                int  oi = __shfl_xor(ci, off, 16);
                if (o1 < c1 || (o1 == c1 && oi < ci)) { c1 = o1; ci = oi; }
            }
            // merge into running result (earlier chunks = lower codes)
            if (c1 < rm1[i] || (c1 == rm1[i] && ci < ridx[i])) { rm1[i] = c1; ridx[i] = ci; }
        }
    }

    if (tx == 0) {
        #pragma unroll
        for (int i = 0; i < 4; ++i) best_idx[row0 + ty * 4 + i] = ridx[i];
    }
}

// z_st = fl(z + fl(z_q - z)) (reference op order), plus f64 loss partials.
__global__ void vq_outputs(const float* __restrict__ z, const float* __restrict__ cb,
                           const int* __restrict__ best_idx, float* __restrict__ out,
                           double* __restrict__ loss_sum)
{
    size_t g = (size_t)blockIdx.x * 256 + threadIdx.x;   // float4 index
    int row = (int)(g >> 6);
    int c4  = (int)(g & 63);
    float4 zv = ((const float4*)z)[g];
    int idx = best_idx[row];
    float4 cv = ((const float4*)(cb + (size_t)idx * DIM))[c4];
    float4 o;
    o.x = zv.x + (cv.x - zv.x);
    o.y = zv.y + (cv.y - zv.y);
    o.z = zv.z + (cv.z - zv.z);
    o.w = zv.w + (cv.w - zv.w);
    ((float4*)out)[g] = o;

    float dx = zv.x - cv.x, dy = zv.y - cv.y, dz = zv.z - cv.z, dw = zv.w - cv.w;
    double ls = (double)dx * dx + (double)dy * dy + (double)dz * dz + (double)dw * dw;
    #pragma unroll
    for (int off = 32; off > 0; off >>= 1) ls += __shfl_down(ls, off);
    if ((threadIdx.x & 63) == 0) atomicAdd(loss_sum, ls);
}

__global__ void vq_write_idx(const int* __restrict__ best_idx, float* __restrict__ out_idx) {
    int r = blockIdx.x * 256 + threadIdx.x;
    out_idx[r] = (float)best_idx[r];
}

__global__ void vq_loss_final(const double* __restrict__ loss_sum, float* __restrict__ out_loss) {
    double m = *loss_sum / (double)(N_TOK * (size_t)DIM);
    float mean = (float)m;
    out_loss[0] = 0.25f * mean + mean;   // commit + codebook, reference op order
}

extern "C" void kernel_launch(void* const* d_in, const int* in_sizes, int n_in,
                              void* d_out, int out_size, void* d_ws, size_t ws_size,
                              hipStream_t stream) {
    const float* z  = (const float*)d_in[0];
    const float* cb = (const float*)d_in[1];
    float* out = (float*)d_out;
    char* ws = (char*)d_ws;

    double* loss_sum = (double*)(ws);
    int*    best_idx = (int*)(ws + 64);
    float*  cnorm    = (float*)(ws + 64 + (size_t)N_TOK * 4);

    vq_init<<<1, 64, 0, stream>>>(loss_sum);
    vq_cnorm<<<KC / 256, 256, 0, stream>>>(cb, cnorm);
    vq_scores<<<N_TOK / TM, 256, 0, stream>>>(z, cb, cnorm, best_idx);
    vq_outputs<<<(N_TOK * (DIM / 4)) / 256, 256, 0, stream>>>(z, cb, best_idx, out, loss_sum);
    vq_write_idx<<<N_TOK / 256, 256, 0, stream>>>(best_idx, out + (size_t)N_TOK * DIM);
    vq_loss_final<<<1, 1, 0, stream>>>(loss_sum, out + (size_t)N_TOK * DIM + N_TOK);
}